// Round 14
// baseline (19137.416 us; speedup 1.0000x reference)
//
#include <hip/hip_runtime.h>

#define HID     32
#define SLEN    65536
#define NB      32
#define UNROLL  16
#define NBLK    (SLEN / UNROLL)
#define RSTRIDE 36   // floats per ring row: 144B = 16B-aligned

typedef float    f32x4 __attribute__((ext_vector_type(4)));
typedef unsigned u32x2 __attribute__((ext_vector_type(2)));

__device__ __forceinline__ float fast_sigmoid(float x) {
    float e = __builtin_amdgcn_exp2f(-1.4426950408889634f * x);
    return __builtin_amdgcn_rcpf(1.0f + e);
}
__device__ __forceinline__ float fast_tanh(float x) {
    float e = __builtin_amdgcn_exp2f(2.8853900817779268f * x);
    return 1.0f - 2.0f * __builtin_amdgcn_rcpf(1.0f + e);
}

// ---- DPP lane-permutation helpers (direction-unambiguous patterns only) ----
#define QP_X1   0xB1   // quad_perm [1,0,3,2]  : lane ^= 1
#define QP_X2   0x4E   // quad_perm [2,3,0,1]  : lane ^= 2
#define ROW_MIR 0x140  // row_mirror           : lane ^= 15 (within 16-row)
#define ROW_HMI 0x141  // row_half_mirror      : lane ^= 7  (within 8-half)
template <int CTRL>
__device__ __forceinline__ float dppf(float v) {
    return __uint_as_float((unsigned)__builtin_amdgcn_mov_dpp(
        (int)__float_as_uint(v), CTRL, 0xF, 0xF, true));
}
// xor-mask emission order of gather16 (shared by weight preload)
__device__ __constant__ const int M_ORD[16] =
    {0,15,7,8, 2,13,5,10, 1,14,6,9, 3,12,4,11};

// Materialize the 16 values of this lane's 16-row: v[s] = base from lane (k ^ M_ORD[s]).
__device__ __forceinline__ void gather16(float b, float v[16]) {
    v[0]  = b;
    v[1]  = dppf<ROW_MIR>(v[0]);    // ^15
    v[2]  = dppf<ROW_HMI>(v[0]);    // ^7
    v[3]  = dppf<ROW_HMI>(v[1]);    // ^8
    v[4]  = dppf<QP_X2 >(v[0]);     // ^2
    v[5]  = dppf<QP_X2 >(v[1]);     // ^13
    v[6]  = dppf<QP_X2 >(v[2]);     // ^5
    v[7]  = dppf<QP_X2 >(v[3]);     // ^10
    v[8]  = dppf<QP_X1 >(v[0]);     // ^1
    v[9]  = dppf<QP_X1 >(v[1]);     // ^14
    v[10] = dppf<QP_X1 >(v[2]);     // ^6
    v[11] = dppf<QP_X1 >(v[3]);     // ^9
    v[12] = dppf<QP_X1 >(v[4]);     // ^3
    v[13] = dppf<QP_X1 >(v[5]);     // ^12
    v[14] = dppf<QP_X1 >(v[6]);     // ^4
    v[15] = dppf<QP_X1 >(v[7]);     // ^11
}

// Half-exchange of raw gate sums — VALIDATED round 10 (bit-exact vs shuffles).
#if __has_builtin(__builtin_amdgcn_permlane32_swap)
__device__ __forceinline__ void half_exchange(float g, bool, float& low_own, float& up_own) {
    u32x2 r = __builtin_amdgcn_permlane32_swap(__float_as_uint(g), __float_as_uint(g), false, false);
    low_own = __uint_as_float(r.x);
    up_own  = __uint_as_float(r.y);
}
#else
__device__ __forceinline__ void half_exchange(float g, bool lo, float& low_own, float& up_own) {
    const float p = __shfl_xor(g, 32, 64);
    low_own = lo ? g : p;
    up_own  = lo ? p : g;
}
#endif

// ROUND-10-VALIDATED DATAFLOW; h-broadcast moved off LDS onto the VALU pipe.
// One wave per batch element. Lane l owns W_hh rows l and l+64 (torch i,f,g,o):
// lanes 0-31 (i_k,g_k), lanes 32-63 (f_k,o_k), k=lane&31. ALL lanes redundantly
// maintain the same c/h (validated r1/7/9/10). Per step the 32 h-values are
// gathered into registers by a 5-level tree: 1 __shfl_xor(h,16) (validated; DS
// latency hidden under the concurrent own-row work) + 30 mov_dpp ops with
// direction-unambiguous patterns; weights were preloaded PRE-PERMUTED to the
// tree's emission order (w[s] = W[row][k ^ M_ORD[s] ^ {0,16}]), so the dot is
// 64 scalar FMAs in 8 independent chains. LDS is WRITE-ONLY in the hot loop
// (y-ring, read once per 16 steps by the r1-validated bulk y-pass). x is
// double-buffered in registers one block ahead. Single wave -> no barriers.
__global__ __launch_bounds__(64, 1) void lstm_scan_kernel(
    const float* __restrict__ x,      // (B, 1, S)
    const float* __restrict__ W_ih,   // (128, 1)
    const float* __restrict__ W_hh,   // (128, 32)
    const float* __restrict__ b_ih,   // (128,)
    const float* __restrict__ b_hh,   // (128,)
    const float* __restrict__ W_lin,  // (1, 32)
    const float* __restrict__ b_lin,  // (1,)
    float* __restrict__ out)          // (B, 1, S)
{
    const int  b    = blockIdx.x;
    const int  lane = threadIdx.x;     // 0..63
    const int  k    = lane & 31;
    const bool lo   = (lane < 32);

    __shared__ __align__(16) float hlds[UNROLL * RSTRIDE];   // write-only ring (y-pass)

    // ---- one-time preload: W_hh rows lane & lane+64, PRE-PERMUTED to tree order ----
    const float* Wr0 = W_hh + lane * HID;
    const float* Wr1 = W_hh + (lane + 64) * HID;
    float wa[16], wa2[16], wb[16], wb2[16];
    #pragma unroll
    for (int s = 0; s < 16; ++s) {
        const int j0 = k ^ M_ORD[s];          // own-row source
        const int j1 = j0 ^ 16;               // other-row source
        wa [s] = Wr0[j0];  wa2[s] = Wr0[j1];
        wb [s] = Wr1[j0];  wb2[s] = Wr1[j1];
    }
    const float bias0 = b_ih[lane]      + b_hh[lane];
    const float bias1 = b_ih[lane + 64] + b_hh[lane + 64];
    const float wih0  = W_ih[lane];
    const float wih1  = W_ih[lane + 64];
    const float blin  = b_lin[0];

    // y-pass (r1-validated shape): lane l covers ring slot l>>2, k-range (l&3)*8
    const int ys = lane >> 2;
    const int yr = (lane & 3) << 3;
    float wl[8];
    #pragma unroll
    for (int j = 0; j < 8; ++j) wl[j] = W_lin[yr + j];

    float hcur = 0.0f, ccur = 0.0f;
    const float* __restrict__ xb = x   + (size_t)b * SLEN;
    float* __restrict__       ob = out + (size_t)b * SLEN;

    // x double buffer: current block in xc[], next block prefetched
    f32x4 xc[4];
    {
        const f32x4* xg = (const f32x4*)xb;
        #pragma unroll
        for (int q = 0; q < 4; ++q) xc[q] = xg[q];
    }

    #pragma unroll 1
    for (int blk = 0; blk < NBLK; ++blk) {
        const int nb_ = (blk + 1 < NBLK) ? (blk + 1) : blk;
        const f32x4* xg = (const f32x4*)(xb + nb_ * UNROLL);
        f32x4 xn0 = xg[0], xn1 = xg[1], xn2 = xg[2], xn3 = xg[3];

        #pragma unroll
        for (int u = 0; u < UNROLL; ++u) {
            const float xt = xc[u >> 2][u & 3];

            // other-row root first (DS latency overlaps the own-row tree+FMAs)
            const float hx = __shfl_xor(hcur, 16, 64);
            float v[16], w_[16];
            gather16(hcur, v);     // own-row 16 values
            gather16(hx,  w_);     // other-row 16 values

            // 8 independent FMA chains of 8
            float Av0 = fmaf(xt, wih0, bias0), Av1 = 0.0f, Au0 = 0.0f, Au1 = 0.0f;
            float Bv0 = fmaf(xt, wih1, bias1), Bv1 = 0.0f, Bu0 = 0.0f, Bu1 = 0.0f;
            #pragma unroll
            for (int s = 0; s < 8; ++s) {
                Av0 = fmaf(v [s],     wa [s],     Av0);
                Av1 = fmaf(v [s + 8], wa [s + 8], Av1);
                Au0 = fmaf(w_[s],     wa2[s],     Au0);
                Au1 = fmaf(w_[s + 8], wa2[s + 8], Au1);
                Bv0 = fmaf(v [s],     wb [s],     Bv0);
                Bv1 = fmaf(v [s + 8], wb [s + 8], Bv1);
                Bu0 = fmaf(w_[s],     wb2[s],     Bu0);
                Bu1 = fmaf(w_[s + 8], wb2[s + 8], Bu1);
            }
            const float g0 = (Av0 + Av1) + (Au0 + Au1);   // lower: i_k  upper: f_k
            const float g1 = (Bv0 + Bv1) + (Bu0 + Bu1);   // lower: g_k  upper: o_k

            float gi, gf, gg, go;
            half_exchange(g0, lo, gi, gf);
            half_exchange(g1, lo, gg, go);

            // ALL lanes redundantly maintain the same c (validated dataflow)
            ccur = fmaf(fast_sigmoid(gf), ccur, fast_sigmoid(gi) * fast_tanh(gg));
            hcur = fast_sigmoid(go) * fast_tanh(ccur);
            if (lo) hlds[u * RSTRIDE + k] = hcur;          // write-only (y-ring)
        }

        // bulk y-pass for this block's 16 h vectors (r1-validated shape)
        {
            const f32x4* yp = (const f32x4*)(hlds + ys * RSTRIDE + yr);
            const f32x4 h0 = yp[0], h1 = yp[1];
            float acc;
            acc = h0.x * wl[0];
            acc = fmaf(h0.y, wl[1], acc); acc = fmaf(h0.z, wl[2], acc); acc = fmaf(h0.w, wl[3], acc);
            acc = fmaf(h1.x, wl[4], acc); acc = fmaf(h1.y, wl[5], acc);
            acc = fmaf(h1.z, wl[6], acc); acc = fmaf(h1.w, wl[7], acc);
            acc += __shfl_xor(acc, 1, 64);
            acc += __shfl_xor(acc, 2, 64);
            if ((lane & 3) == 0) ob[blk * UNROLL + ys] = fast_tanh(acc + blin);
        }

        xc[0] = xn0; xc[1] = xn1; xc[2] = xn2; xc[3] = xn3;
    }
}

extern "C" void kernel_launch(void* const* d_in, const int* in_sizes, int n_in,
                              void* d_out, int out_size, void* d_ws, size_t ws_size,
                              hipStream_t stream) {
    (void)d_ws; (void)ws_size; (void)in_sizes; (void)n_in; (void)out_size;
    const float* x     = (const float*)d_in[0];
    const float* W_ih  = (const float*)d_in[1];
    const float* W_hh  = (const float*)d_in[2];
    const float* b_ih  = (const float*)d_in[3];
    const float* b_hh  = (const float*)d_in[4];
    const float* W_lin = (const float*)d_in[5];
    const float* b_lin = (const float*)d_in[6];
    float* out = (float*)d_out;

    hipLaunchKernelGGL(lstm_scan_kernel, dim3(NB), dim3(64), 0, stream,
                       x, W_ih, W_hh, b_ih, b_hh, W_lin, b_lin, out);
}